// Round 4
// baseline (565.049 us; speedup 1.0000x reference)
//
#include <hip/hip_runtime.h>
#include <stdint.h>

// CasualSelfAttention (buggy reference preserved): B=4, S=4096, D=768.
// Inputs are fp32 per the reference (sniffed at runtime, defensively); internal
// compute bf16 MFMA; OUTPUT dtype keyed on the sniffed flag (fp32 in -> fp32 out).
// Pipeline: sniff -> normalize to bf16 -> QKV proj GEMMs (v stored transposed)
// -> per-group: S=q@k^T, row softmax, yT = vT@P^T (into dead q slots; yT flat
// == reference's transpose(1,2).reshape permutation) -> out = y' @ Wc^T + bc.
//
// R3 result: R2(glds16) and R3(manual staging) were bit-identical => glds16
// staging is correct; restored here. R4 change: final GEMM writes fp32 when
// inputs sniffed fp32.
//
// ws layout:
//   OFF_Q   = 0          q [B][S][D]; batch slots later reused as yT_b [D][S]
//   OFF_K   = 25165824   k [B][S][D]
//   OFF_VT  = 50331648   vT2 [D][B*S]  (v projection stored transposed)
//   OFF_W   = 75497472   normalized Wq,Wk,Wv,Wc (4 x 1179648 B)
//   OFF_B   = 80216064   normalized bq,bk,bv,bc (4 x 1536 B)
//   OFF_FLAG= 80222208   dtype flag (int)
//   OFF_ATT = 80223232   att [group][S][S] bf16 (xn aliases its head)

typedef __bf16 bf16;
typedef __bf16 bf16x4 __attribute__((ext_vector_type(4)));
typedef __bf16 bf16x8 __attribute__((ext_vector_type(8)));
typedef float f32x4 __attribute__((ext_vector_type(4)));

#define OFF_Q    0L
#define OFF_K    25165824L
#define OFF_VT   50331648L
#define OFF_W    75497472L
#define OFF_B    80216064L
#define OFF_FLAG 80222208L
#define OFF_ATT  80223232L
#define ATT_B    33554432L   // one batch of att, bytes
#define SD       3145728L    // 4096*768 elements

__device__ __forceinline__ void glds16(const void* g, void* s) {
  __builtin_amdgcn_global_load_lds((const __attribute__((address_space(1))) void*)g,
                                   (__attribute__((address_space(3))) void*)s, 16, 0, 0);
}

// fp32-vs-bf16 sniffer: low uint16 halves of fp32 words have uniform exponent
// bits (p~1/8 per sample of e>=0xE0); true-bf16 N(0,1) data never trips.
__global__ void sniff_dtype(const uint16_t* __restrict__ x, int* __restrict__ flag)
{
  const int t = threadIdx.x;
  int bad = 0;
  for (int i = t; i < 4096; i += 256) {
    const int e = (x[2 * i] >> 7) & 0xFF;
    bad |= (e >= 0xE0);
  }
  __shared__ int s;
  if (t == 0) s = 0;
  __syncthreads();
  if (bad) s = 1;
  __syncthreads();
  if (t == 0) *flag = s;
}

__global__ void normalize8(const void* __restrict__ src, bf16* __restrict__ dst,
                           long n8, const int* __restrict__ flag)
{
  const long i = (long)blockIdx.x * 256 + threadIdx.x;
  if (i >= n8) return;
  bf16x8 o;
  if (*flag) {
    const float4 a = ((const float4*)src)[2 * i];
    const float4 b = ((const float4*)src)[2 * i + 1];
    o[0] = (bf16)a.x; o[1] = (bf16)a.y; o[2] = (bf16)a.z; o[3] = (bf16)a.w;
    o[4] = (bf16)b.x; o[5] = (bf16)b.y; o[6] = (bf16)b.z; o[7] = (bf16)b.w;
  } else {
    o = ((const bf16x8*)src)[i];
  }
  ((bf16x8*)dst)[i] = o;
}

// C[m][n] = alpha*(sum_k A[m][k]*Bm[n][k] + bias[n]); bf16 in, fp32 accum.
// transC: store bf16 C[n*ldc+m] (packed 4-row 8B stores).
// oflag: if non-null and *oflag, C is fp32; else bf16.
// 128x128 tile (4 waves 2x2, each 64x64 = 4x4 MFMA 16x16x32), BK=32, glds16 staging.
__launch_bounds__(256, 2)
__global__ void gemm_bt(const bf16* __restrict__ A, int lda, long strideA,
                        const bf16* __restrict__ Bm, int ldb, long strideB,
                        void* __restrict__ Cv, int ldc, long strideC,
                        int K, const bf16* __restrict__ bias, float alpha,
                        int transC, const int* __restrict__ oflag)
{
  __shared__ bf16 As[128 * 32];
  __shared__ bf16 Bs[128 * 32];
  A  += (long)blockIdx.z * strideA;
  Bm += (long)blockIdx.z * strideB;
  const int outf32 = (oflag != nullptr) && (*oflag != 0);
  const int tid = threadIdx.x;
  const int wave = tid >> 6, lane = tid & 63;
  const int lr = lane & 15, quad = lane >> 4;
  const int wm = (wave >> 1) * 64, wn = (wave & 1) * 64;
  const long m0 = (long)blockIdx.y * 128, n0 = (long)blockIdx.x * 128;

  f32x4 acc[4][4];
  const f32x4 zero = {0.f, 0.f, 0.f, 0.f};
#pragma unroll
  for (int i = 0; i < 4; ++i)
#pragma unroll
    for (int j = 0; j < 4; ++j) acc[i][j] = zero;

  // glds16 dest identity: wave base + lane*16B == (tid>>2)*32 + (tid&3)*8 elems.
  const int r0 = tid >> 2, c0 = (tid & 3) * 8;
  const bf16* pA0 = A + (m0 + r0) * (long)lda + c0;
  const bf16* pA1 = A + (m0 + 64 + r0) * (long)lda + c0;
  const bf16* pB0 = Bm + (n0 + r0) * (long)ldb + c0;
  const bf16* pB1 = Bm + (n0 + 64 + r0) * (long)ldb + c0;
  bf16* sA0 = As + wave * 512;
  bf16* sA1 = As + 2048 + wave * 512;
  bf16* sB0 = Bs + wave * 512;
  bf16* sB1 = Bs + 2048 + wave * 512;

  for (int k0 = 0; k0 < K; k0 += 32) {
    __syncthreads();
    glds16(pA0 + k0, sA0);
    glds16(pA1 + k0, sA1);
    glds16(pB0 + k0, sB0);
    glds16(pB1 + k0, sB1);
    __syncthreads();
    bf16x8 aF[4], bF[4];
#pragma unroll
    for (int i = 0; i < 4; ++i) {
      aF[i] = *(const bf16x8*)(As + (wm + i * 16 + lr) * 32 + quad * 8);
      bF[i] = *(const bf16x8*)(Bs + (wn + i * 16 + lr) * 32 + quad * 8);
    }
#pragma unroll
    for (int i = 0; i < 4; ++i)
#pragma unroll
      for (int j = 0; j < 4; ++j)
        acc[i][j] = __builtin_amdgcn_mfma_f32_16x16x32_bf16(aF[i], bF[j], acc[i][j], 0, 0, 0);
  }

  // C/D layout (m89-verified): col = lane&15, row = quad*4 + reg.
#pragma unroll
  for (int j = 0; j < 4; ++j) {
    const long col = n0 + wn + j * 16 + lr;
    const float bv = bias ? (float)bias[col] : 0.f;
#pragma unroll
    for (int i = 0; i < 4; ++i) {
      const long row = m0 + wm + i * 16 + quad * 4;
      if (transC) {
        bf16x4 v4;
#pragma unroll
        for (int r = 0; r < 4; ++r) v4[r] = (bf16)((acc[i][j][r] + bv) * alpha);
        *(bf16x4*)((bf16*)Cv + (long)blockIdx.z * strideC + col * (long)ldc + row) = v4;
      } else if (outf32) {
#pragma unroll
        for (int r = 0; r < 4; ++r)
          ((float*)Cv)[(long)blockIdx.z * strideC + (row + r) * (long)ldc + col] =
              (acc[i][j][r] + bv) * alpha;
      } else {
#pragma unroll
        for (int r = 0; r < 4; ++r)
          ((bf16*)Cv)[(long)blockIdx.z * strideC + (row + r) * (long)ldc + col] =
              (bf16)((acc[i][j][r] + bv) * alpha);
      }
    }
  }
}

// One 4096-wide row per block; 256 thr x 16 elements; fp32 reduce, bf16 in/out.
__launch_bounds__(256)
__global__ void softmax_rows(bf16* __restrict__ att)
{
  bf16* p = att + (size_t)blockIdx.x * 4096;
  const int t = threadIdx.x;
  bf16x8 v0 = *(const bf16x8*)(p + t * 16);
  bf16x8 v1 = *(const bf16x8*)(p + t * 16 + 8);
  float x[16];
#pragma unroll
  for (int i = 0; i < 8; ++i) { x[i] = (float)v0[i]; x[8 + i] = (float)v1[i]; }
  float m = x[0];
#pragma unroll
  for (int i = 1; i < 16; ++i) m = fmaxf(m, x[i]);
#pragma unroll
  for (int off = 32; off > 0; off >>= 1) m = fmaxf(m, __shfl_down(m, off));
  __shared__ float redm[4], reds[4];
  if ((t & 63) == 0) redm[t >> 6] = m;
  __syncthreads();
  m = fmaxf(fmaxf(redm[0], redm[1]), fmaxf(redm[2], redm[3]));
  float s = 0.f;
#pragma unroll
  for (int i = 0; i < 16; ++i) { x[i] = __expf(x[i] - m); s += x[i]; }
#pragma unroll
  for (int off = 32; off > 0; off >>= 1) s += __shfl_down(s, off);
  if ((t & 63) == 0) reds[t >> 6] = s;
  __syncthreads();
  s = reds[0] + reds[1] + reds[2] + reds[3];
  const float inv = 1.f / s;
#pragma unroll
  for (int i = 0; i < 8; ++i) { v0[i] = (bf16)(x[i] * inv); v1[i] = (bf16)(x[8 + i] * inv); }
  *(bf16x8*)(p + t * 16) = v0;
  *(bf16x8*)(p + t * 16 + 8) = v1;
}

extern "C" void kernel_launch(void* const* d_in, const int* in_sizes, int n_in,
                              void* d_out, int out_size, void* d_ws, size_t ws_size,
                              hipStream_t stream)
{
  (void)in_sizes; (void)n_in; (void)out_size;
  char* ws = (char*)d_ws;

  if (ws_size < (size_t)(OFF_ATT + ATT_B)) return;  // out stays 0 -> 0.157 diagnostic
  const size_t avail = ws_size - (size_t)OFF_ATT;
  int group = (int)(avail / (size_t)ATT_B);
  group = group >= 4 ? 4 : (group >= 2 ? 2 : 1);

  bf16* q   = (bf16*)(ws + OFF_Q);    // later: yT slots / y' flat
  bf16* k   = (bf16*)(ws + OFF_K);
  bf16* vT2 = (bf16*)(ws + OFF_VT);   // [768][16384]
  bf16* Wn  = (bf16*)(ws + OFF_W);    // 4 x 589824
  bf16* bn  = (bf16*)(ws + OFF_B);    // 4 x 768
  int*  flg = (int*)(ws + OFF_FLAG);
  bf16* att = (bf16*)(ws + OFF_ATT);
  bf16* xn  = att;                    // alias: dead before att is written

  dim3 blk(256, 1, 1);
  const float qs = 0.03608439182435161f;  // 768^-0.5

  // 1) dtype sniff + normalize all 9 inputs to bf16.
  sniff_dtype<<<1, blk, 0, stream>>>((const uint16_t*)d_in[0], flg);
  normalize8<<<6144, blk, 0, stream>>>(d_in[0], xn, 1572864L, flg);
  for (int w = 0; w < 4; ++w) {
    normalize8<<<288, blk, 0, stream>>>(d_in[1 + 2 * w], Wn + w * 589824L, 73728L, flg);
    normalize8<<<1, blk, 0, stream>>>(d_in[2 + 2 * w], bn + w * 768L, 96L, flg);
  }

  // 2) QKV projections: M=16384, N=768, K=768. v stored transposed into vT2.
  dim3 gproj(6, 128, 1);
  gemm_bt<<<gproj, blk, 0, stream>>>(xn, 768, 0, Wn + 0 * 589824L, 768, 0,
                                     q, 768, 0, 768, bn + 0, qs, 0, nullptr);
  gemm_bt<<<gproj, blk, 0, stream>>>(xn, 768, 0, Wn + 1 * 589824L, 768, 0,
                                     k, 768, 0, 768, bn + 768, 1.f, 0, nullptr);
  gemm_bt<<<gproj, blk, 0, stream>>>(xn, 768, 0, Wn + 2 * 589824L, 768, 0,
                                     vT2, 16384, 0, 768, bn + 1536, 1.f, 1, nullptr);

  // 3) Attention per group of batches.
  for (int g = 0; g < 4; g += group) {
    dim3 gs(32, 32, group);
    gemm_bt<<<gs, blk, 0, stream>>>(q + g * SD, 768, SD, k + g * SD, 768, SD,
                                    att, 4096, 16777216L, 768, nullptr, 1.f, 0, nullptr);
    softmax_rows<<<group * 4096, blk, 0, stream>>>(att);
    dim3 gpv(32, 6, group);
    gemm_bt<<<gpv, blk, 0, stream>>>(vT2 + g * 4096L, 16384, 4096L,
                                     att, 4096, 16777216L,
                                     q + g * SD, 4096, SD, 4096, nullptr, 1.f, 0, nullptr);
  }

  // 4) out = y' @ Wc^T + bc  (q region flat == y' [16384][768]); output dtype
  //    keyed on sniffed input dtype (fp32 in -> fp32 out).
  dim3 gout(6, 128, 1);
  gemm_bt<<<gout, blk, 0, stream>>>(q, 768, 0, Wn + 3 * 589824L, 768, 0,
                                    d_out, 768, 0, 768, bn + 2304, 1.f, 0, flg);
}